// Round 5
// baseline (154.966 us; speedup 1.0000x reference)
//
#include <hip/hip_runtime.h>
#include <hip/hip_cooperative_groups.h>

namespace cg = cooperative_groups;

#define BB 2
#define TT 1024
#define DD 512
#define HH 8
#define FF 16
#define HDIM 64
#define BT (BB*TT)   // 2048

typedef short bf16x8 __attribute__((ext_vector_type(8)));
typedef float f32x4  __attribute__((ext_vector_type(4)));
#define MFMA_BF16 __builtin_amdgcn_mfma_f32_16x16x32_bf16

// float -> bf16 round-to-nearest-even
__device__ __forceinline__ ushort f2b(float f) {
    uint u = __float_as_uint(f);
    uint r = (u + 0x7fffu + ((u >> 16) & 1u)) >> 16;
    return (ushort)r;
}

// ---------------------------------------------------------------------------
// One cooperative kernel, 4 phases separated by grid.sync():
//   0: cast X,Wq|Wk|Wv,Wo -> bf16
//   1: QKV projection (bf16 MFMA, fragments from global/L2)
//   2: causal Taylor attention (dedup'd: each wave owns a 32-key half)
//   3: output projection
// 256 blocks x 256 threads, 1 block/CU.
// ---------------------------------------------------------------------------
__global__ __launch_bounds__(256) void fused_kernel(
    const float* __restrict__ X,  const float* __restrict__ Wq,
    const float* __restrict__ Wk, const float* __restrict__ Wv,
    const float* __restrict__ Wo,
    ushort* __restrict__ Xb, ushort* __restrict__ Wb, ushort* __restrict__ Wob,
    ushort* __restrict__ Qb, ushort* __restrict__ Kb, ushort* __restrict__ Vtg,
    ushort* __restrict__ Yb, float* __restrict__ Out)
{
    cg::grid_group grid = cg::this_grid();

    __shared__ short Vt[2][64][72];   // phase2: [qsel][v][k64+8pad]; epilogue: f32 scratch qsel0
    __shared__ short Pl[4][32][72];   // phase2: [wave][q32][k64+8pad]; epilogue: f32 scratch qsel1

    const int tid = threadIdx.x;
    const int bid = blockIdx.x;
    const int w = tid >> 6, l = tid & 63;
    const int lr = l & 15, g = l >> 4;

    // ---------------- phase 0: cast to bf16 ----------------
    {
        const int gtid = bid * 256 + tid;
        for (int u = gtid; u < 425984; u += 65536) {
            const int i4 = u * 4;
            const float* src; ushort* dst;
            if (i4 < 1048576)      { src = X  + i4;             dst = Xb + i4; }
            else if (i4 < 1114112) { src = Wq + (i4 - 1048576); dst = Wb + (i4 - 1048576); }
            else if (i4 < 1179648) { src = Wk + (i4 - 1114112); dst = Wb + 65536 + (i4 - 1114112); }
            else if (i4 < 1441792) { src = Wv + (i4 - 1179648); dst = Wb + 131072 + (i4 - 1179648); }
            else                   { src = Wo + (i4 - 1441792); dst = Wob + (i4 - 1441792); }
            float4 v = *(const float4*)src;
            ushort4 o = { f2b(v.x), f2b(v.y), f2b(v.z), f2b(v.w) };
            *(ushort4*)dst = o;
        }
    }
    grid.sync();

    // ---------------- phase 1: QKV projection ----------------
    if (bid < 192) {
        const int m0 = (bid & 31) * 64, n0 = (bid >> 5) * 128;
        const int mw = w & 1, nw = w >> 1;

        f32x4 acc[2][4] = {};
        const ushort* Ar = Xb + (size_t)(m0 + mw*32 + lr) * 512 + g*8;
        const ushort* Br = Wb + (size_t)(n0 + nw*64 + lr) * 512 + g*8;

        #pragma unroll 4
        for (int ks = 0; ks < 16; ++ks) {
            bf16x8 a0 = *(const bf16x8*)(Ar + ks*32);
            bf16x8 a1 = *(const bf16x8*)(Ar + (size_t)16*512 + ks*32);
            bf16x8 b0 = *(const bf16x8*)(Br + ks*32);
            bf16x8 b1 = *(const bf16x8*)(Br + (size_t)16*512 + ks*32);
            bf16x8 b2 = *(const bf16x8*)(Br + (size_t)32*512 + ks*32);
            bf16x8 b3 = *(const bf16x8*)(Br + (size_t)48*512 + ks*32);
            acc[0][0] = MFMA_BF16(a0, b0, acc[0][0], 0, 0, 0);
            acc[0][1] = MFMA_BF16(a0, b1, acc[0][1], 0, 0, 0);
            acc[0][2] = MFMA_BF16(a0, b2, acc[0][2], 0, 0, 0);
            acc[0][3] = MFMA_BF16(a0, b3, acc[0][3], 0, 0, 0);
            acc[1][0] = MFMA_BF16(a1, b0, acc[1][0], 0, 0, 0);
            acc[1][1] = MFMA_BF16(a1, b1, acc[1][1], 0, 0, 0);
            acc[1][2] = MFMA_BF16(a1, b2, acc[1][2], 0, 0, 0);
            acc[1][3] = MFMA_BF16(a1, b3, acc[1][3], 0, 0, 0);
        }

        if (n0 < 256) {
            ushort* Dst = (n0 == 0) ? Qb : Kb;
            #pragma unroll
            for (int mb = 0; mb < 2; ++mb)
                #pragma unroll
                for (int nb = 0; nb < 4; ++nb) {
                    const int n = nw*64 + nb*16 + lr;
                    const int h = n >> 4, f = n & 15;
                    #pragma unroll
                    for (int r = 0; r < 4; ++r) {
                        const int tok = m0 + mw*32 + mb*16 + g*4 + r;
                        const int b = tok >> 10, tt = tok & 1023;
                        Dst[(((size_t)(b*HH + h)) * TT + tt) * FF + f] = f2b(acc[mb][nb][r]);
                    }
                }
        } else {
            #pragma unroll
            for (int mb = 0; mb < 2; ++mb)
                #pragma unroll
                for (int nb = 0; nb < 4; ++nb) {
                    const int n = n0 + nw*64 + nb*16 + lr - 256;
                    const int h = n >> 6, v = n & 63;
                    const int tok0 = m0 + mw*32 + mb*16 + g*4;
                    const int b = tok0 >> 10, tt = tok0 & 1023;
                    uint lo = (uint)f2b(acc[mb][nb][0]) | ((uint)f2b(acc[mb][nb][1]) << 16);
                    uint hi = (uint)f2b(acc[mb][nb][2]) | ((uint)f2b(acc[mb][nb][3]) << 16);
                    uint2 pk = { lo, hi };
                    *(uint2*)&Vtg[(((size_t)(b*HH + h)) * 64 + v) * TT + tt] = pk;
                }
        }
    }
    grid.sync();

    // ---------------- phase 2: attention ----------------
    {
        const int qp = bid & 15, bh = bid >> 4;
        const int b = bh >> 3, h = bh & 7;
        const int qsel = w >> 1, vh = w & 1;
        const int qt = qsel ? (31 - qp) : qp;
        const int nkc = (qt >> 1) + 1;
        const bf16x8 zf = {0,0,0,0,0,0,0,0};

        bf16x8 qf[2];
        #pragma unroll
        for (int nb = 0; nb < 2; ++nb)
            qf[nb] = (l < 32)
                ? *(const bf16x8*)(Qb + ((size_t)bh*TT + qt*32 + nb*16 + lr)*FF + g*8)
                : zf;

        f32x4 o[4][2] = {};         // o[mv][nb]: partial O^T over this wave's key-half
        float den[2] = {0.f, 0.f};

        for (int kc = 0; kc < nkc; ++kc) {
            // stage ALL 64 V rows x this wave's 32 k-cols (wave-local RAW only)
            {
                const ushort* src = Vtg + ((size_t)bh*64 + l)*TT + kc*64 + vh*32;
                short* dstp = &Vt[qsel][l][vh*32];
                *(bf16x8*)(dstp)      = *(const bf16x8*)(src);
                *(bf16x8*)(dstp + 8)  = *(const bf16x8*)(src + 8);
                *(bf16x8*)(dstp + 16) = *(const bf16x8*)(src + 16);
                *(bf16x8*)(dstp + 24) = *(const bf16x8*)(src + 24);
            }

            // S^T for this wave's 32 keys (mb in {2vh, 2vh+1}); poly+mask+den; pack -> P
            #pragma unroll
            for (int mbi = 0; mbi < 2; ++mbi) {
                const int mb = vh*2 + mbi;
                bf16x8 kf = (l < 32)
                    ? *(const bf16x8*)(Kb + ((size_t)bh*TT + kc*64 + mb*16 + lr)*FF + g*8)
                    : zf;
                #pragma unroll
                for (int nb = 0; nb < 2; ++nb) {
                    f32x4 z4 = {};
                    f32x4 s = MFMA_BF16(kf, qf[nb], z4, 0, 0, 0);
                    const int qg = qt*32 + nb*16 + lr;
                    const int kg0 = kc*64 + mb*16 + g*4;
                    float pv[4];
                    #pragma unroll
                    for (int r = 0; r < 4; ++r) {
                        float ss = s[r] * 0.25f;
                        float pp = fmaf(ss, fmaf(ss, 0.5f, 1.0f), 1.0f);
                        if (kg0 + r > qg) pp = 0.f;
                        den[nb] += pp;
                        pv[r] = pp;
                    }
                    uint2 pk = { (uint)f2b(pv[0]) | ((uint)f2b(pv[1]) << 16),
                                 (uint)f2b(pv[2]) | ((uint)f2b(pv[3]) << 16) };
                    *(uint2*)&Pl[w][nb*16 + lr][mb*16 + g*4] = pk;
                }
            }

            // O partial += V(all 64 rows, this k-half) . P(this k-half)
            #pragma unroll
            for (int mv = 0; mv < 4; ++mv) {
                bf16x8 vf = *(const bf16x8*)&Vt[qsel][mv*16 + lr][vh*32 + g*8];
                #pragma unroll
                for (int nb = 0; nb < 2; ++nb) {
                    bf16x8 pf = *(const bf16x8*)&Pl[w][nb*16 + lr][vh*32 + g*8];
                    o[mv][nb] = MFMA_BF16(vf, pf, o[mv][nb], 0, 0, 0);
                }
            }
        }

        // wave-level den reduce (covers this wave's key-half)
        float dred[2];
        #pragma unroll
        for (int nb = 0; nb < 2; ++nb) {
            float d = den[nb];
            d += __shfl_xor(d, 16);
            d += __shfl_xor(d, 32);
            dred[nb] = d;
        }

        __syncthreads();   // all waves done reading Vt/Pl as bf16

        // write O/den partials to f32 LDS scratch (qsel0 -> Vt, qsel1 -> Pl)
        float* sc = qsel ? (float*)&Pl[0][0][0] : (float*)&Vt[0][0][0];
        #pragma unroll
        for (int mv = 0; mv < 4; ++mv)
            #pragma unroll
            for (int nb = 0; nb < 2; ++nb)
                *(f32x4*)&sc[(((vh*4 + mv)*2 + nb)*64 + l)*4] = o[mv][nb];
        if (g == 0) {
            sc[4096 + (vh*2 + 0)*16 + lr] = dred[0];
            sc[4096 + (vh*2 + 1)*16 + lr] = dred[1];
        }

        __syncthreads();

        // combine the two key-halves, normalize, store bf16 Y
        #pragma unroll
        for (int nb = 0; nb < 2; ++nb) {
            const float dtot = sc[4096 + nb*16 + lr] + sc[4096 + 32 + nb*16 + lr];
            const float inv = 1.0f / (dtot + 1e-12f);
            const int t = qt*32 + nb*16 + lr;
            #pragma unroll
            for (int mvo = 0; mvo < 2; ++mvo) {
                const int gmv = vh*2 + mvo;
                const float* p0 = &sc[((gmv*2 + nb)*64 + l)*4];
                const float* p1 = &sc[(((4 + gmv)*2 + nb)*64 + l)*4];
                const float ov0 = (p0[0] + p1[0]) * inv;
                const float ov1 = (p0[1] + p1[1]) * inv;
                const float ov2 = (p0[2] + p1[2]) * inv;
                const float ov3 = (p0[3] + p1[3]) * inv;
                uint2 pk = { (uint)f2b(ov0) | ((uint)f2b(ov1) << 16),
                             (uint)f2b(ov2) | ((uint)f2b(ov3) << 16) };
                *(uint2*)(Yb + ((size_t)(b*TT + t))*DD + h*HDIM + vh*32 + mvo*16 + g*4) = pk;
            }
        }
    }
    grid.sync();

    // ---------------- phase 3: output projection ----------------
    {
        const int m0 = (bid & 31) * 64, n0 = (bid >> 5) * 64;
        const int mw = w & 1, nw = w >> 1;

        f32x4 acc[2][2] = {};
        const ushort* Ar = Yb  + (size_t)(m0 + mw*32 + lr) * 512 + g*8;
        const ushort* Br = Wob + (size_t)(n0 + nw*32 + lr) * 512 + g*8;

        #pragma unroll 4
        for (int ks = 0; ks < 16; ++ks) {
            bf16x8 a0 = *(const bf16x8*)(Ar + ks*32);
            bf16x8 a1 = *(const bf16x8*)(Ar + (size_t)16*512 + ks*32);
            bf16x8 b0 = *(const bf16x8*)(Br + ks*32);
            bf16x8 b1 = *(const bf16x8*)(Br + (size_t)16*512 + ks*32);
            acc[0][0] = MFMA_BF16(a0, b0, acc[0][0], 0, 0, 0);
            acc[0][1] = MFMA_BF16(a0, b1, acc[0][1], 0, 0, 0);
            acc[1][0] = MFMA_BF16(a1, b0, acc[1][0], 0, 0, 0);
            acc[1][1] = MFMA_BF16(a1, b1, acc[1][1], 0, 0, 0);
        }

        #pragma unroll
        for (int mb = 0; mb < 2; ++mb)
            #pragma unroll
            for (int nb = 0; nb < 2; ++nb) {
                const int n = n0 + nw*32 + nb*16 + lr;
                const int m = m0 + mw*32 + mb*16 + g*4;
                #pragma unroll
                for (int r = 0; r < 4; ++r)
                    Out[(size_t)(m + r)*512 + n] = acc[mb][nb][r];
            }
    }
}

// ---------------------------------------------------------------------------
extern "C" void kernel_launch(void* const* d_in, const int* in_sizes, int n_in,
                              void* d_out, int out_size, void* d_ws, size_t ws_size,
                              hipStream_t stream) {
    const float* X  = (const float*)d_in[0];   // (2,1024,512)
    const float* Wq = (const float*)d_in[1];   // (128,512)
    const float* Wk = (const float*)d_in[2];   // (128,512)
    const float* Wv = (const float*)d_in[3];   // (512,512)
    const float* Wo = (const float*)d_in[4];   // (512,512)
    float* out = (float*)d_out;                // (2,1024,512)

    ushort* ws = (ushort*)d_ws;
    ushort* Xb  = ws;                    // 2048*512   = 1048576
    ushort* Wb  = Xb  + 1048576;         // 768*512    = 393216
    ushort* Wob = Wb  + 393216;          // 512*512    = 262144
    ushort* Qb  = Wob + 262144;          // 16*1024*16 = 262144
    ushort* Kb  = Qb  + 262144;          // 262144
    ushort* Vtg = Kb  + 262144;          // 16*64*1024 = 1048576
    ushort* Yb  = Vtg + 1048576;         // 2048*512   = 1048576

    void* args[] = {
        (void*)&X, (void*)&Wq, (void*)&Wk, (void*)&Wv, (void*)&Wo,
        (void*)&Xb, (void*)&Wb, (void*)&Wob, (void*)&Qb, (void*)&Kb,
        (void*)&Vtg, (void*)&Yb, (void*)&out
    };
    hipLaunchCooperativeKernel((const void*)fused_kernel,
                               dim3(256), dim3(256), args, 0, stream);
}

// Round 6
// 56.488 us; speedup vs baseline: 2.7433x; 2.7433x over previous
//
#include <hip/hip_runtime.h>

#define BB 2
#define TT 1024
#define DD 512
#define HH 8
#define FF 16
#define HDIM 64
#define BT (BB*TT)   // 2048

typedef short bf16x8 __attribute__((ext_vector_type(8)));
typedef float f32x4  __attribute__((ext_vector_type(4)));
#define MFMA_BF16 __builtin_amdgcn_mfma_f32_16x16x32_bf16

// float -> bf16 round-to-nearest-even
__device__ __forceinline__ ushort f2b(float f) {
    uint u = __float_as_uint(f);
    uint r = (u + 0x7fffu + ((u >> 16) & 1u)) >> 16;
    return (ushort)r;
}

// ---------------------------------------------------------------------------
// Kernel 0: cast inputs to bf16.  X -> Xb; Wq|Wk|Wv -> Wb[768][512]; Wo -> Wob
// ---------------------------------------------------------------------------
__global__ __launch_bounds__(256) void cast_all(
    const float* __restrict__ X,  const float* __restrict__ Wq,
    const float* __restrict__ Wk, const float* __restrict__ Wv,
    const float* __restrict__ Wo,
    ushort* __restrict__ Xb, ushort* __restrict__ Wb, ushort* __restrict__ Wob)
{
    const int i4 = (blockIdx.x * 256 + threadIdx.x) * 4;
    const float* src; ushort* dst;
    if (i4 < 1048576)      { src = X  + i4;             dst = Xb + i4; }
    else if (i4 < 1114112) { src = Wq + (i4 - 1048576); dst = Wb + (i4 - 1048576); }
    else if (i4 < 1179648) { src = Wk + (i4 - 1114112); dst = Wb + 65536 + (i4 - 1114112); }
    else if (i4 < 1441792) { src = Wv + (i4 - 1179648); dst = Wb + 131072 + (i4 - 1179648); }
    else                   { src = Wo + (i4 - 1441792); dst = Wob + (i4 - 1441792); }
    float4 v = *(const float4*)src;
    ushort4 o = { f2b(v.x), f2b(v.y), f2b(v.z), f2b(v.w) };
    *(ushort4*)dst = o;
}

// ---------------------------------------------------------------------------
// Kernel 1: QKV projection, bf16 MFMA, fragments direct from global (L2).
// C[2048 x 768] = Xb @ Wb^T, K=512.  Block tile 64x128, 4 waves (2m x 2n).
// Epilogue: Q,K -> (bh,t,16) bf16;  V -> Vt[bh][64][1024] (pre-transposed).
// ---------------------------------------------------------------------------
__global__ __launch_bounds__(256) void qkv_mfma(
    const ushort* __restrict__ Xb, const ushort* __restrict__ Wb,
    ushort* __restrict__ Qb, ushort* __restrict__ Kb, ushort* __restrict__ Vtg)
{
    const int m0 = blockIdx.x * 64, n0 = blockIdx.y * 128;
    const int tid = threadIdx.x, w = tid >> 6, l = tid & 63;
    const int mw = w & 1, nw = w >> 1, lr = l & 15, g = l >> 4;

    f32x4 acc[2][4] = {};
    const ushort* Ar = Xb + (size_t)(m0 + mw*32 + lr) * 512 + g*8;
    const ushort* Br = Wb + (size_t)(n0 + nw*64 + lr) * 512 + g*8;

    #pragma unroll 4
    for (int ks = 0; ks < 16; ++ks) {
        bf16x8 a0 = *(const bf16x8*)(Ar + ks*32);
        bf16x8 a1 = *(const bf16x8*)(Ar + (size_t)16*512 + ks*32);
        bf16x8 b0 = *(const bf16x8*)(Br + ks*32);
        bf16x8 b1 = *(const bf16x8*)(Br + (size_t)16*512 + ks*32);
        bf16x8 b2 = *(const bf16x8*)(Br + (size_t)32*512 + ks*32);
        bf16x8 b3 = *(const bf16x8*)(Br + (size_t)48*512 + ks*32);
        acc[0][0] = MFMA_BF16(a0, b0, acc[0][0], 0, 0, 0);
        acc[0][1] = MFMA_BF16(a0, b1, acc[0][1], 0, 0, 0);
        acc[0][2] = MFMA_BF16(a0, b2, acc[0][2], 0, 0, 0);
        acc[0][3] = MFMA_BF16(a0, b3, acc[0][3], 0, 0, 0);
        acc[1][0] = MFMA_BF16(a1, b0, acc[1][0], 0, 0, 0);
        acc[1][1] = MFMA_BF16(a1, b1, acc[1][1], 0, 0, 0);
        acc[1][2] = MFMA_BF16(a1, b2, acc[1][2], 0, 0, 0);
        acc[1][3] = MFMA_BF16(a1, b3, acc[1][3], 0, 0, 0);
    }

    if (n0 < 256) {
        ushort* Dst = (n0 == 0) ? Qb : Kb;
        #pragma unroll
        for (int mb = 0; mb < 2; ++mb)
            #pragma unroll
            for (int nb = 0; nb < 4; ++nb) {
                const int n = nw*64 + nb*16 + lr;
                const int h = n >> 4, f = n & 15;
                #pragma unroll
                for (int r = 0; r < 4; ++r) {
                    const int tok = m0 + mw*32 + mb*16 + g*4 + r;
                    const int b = tok >> 10, tt = tok & 1023;
                    Dst[(((size_t)(b*HH + h)) * TT + tt) * FF + f] = f2b(acc[mb][nb][r]);
                }
            }
    } else {
        #pragma unroll
        for (int mb = 0; mb < 2; ++mb)
            #pragma unroll
            for (int nb = 0; nb < 4; ++nb) {
                const int n = n0 + nw*64 + nb*16 + lr - 256;
                const int h = n >> 6, v = n & 63;
                const int tok0 = m0 + mw*32 + mb*16 + g*4;
                const int b = tok0 >> 10, tt = tok0 & 1023;
                uint lo = (uint)f2b(acc[mb][nb][0]) | ((uint)f2b(acc[mb][nb][1]) << 16);
                uint hi = (uint)f2b(acc[mb][nb][2]) | ((uint)f2b(acc[mb][nb][3]) << 16);
                uint2 pk = { lo, hi };
                *(uint2*)&Vtg[(((size_t)(b*HH + h)) * 64 + v) * TT + tt] = pk;
            }
    }
}

// ---------------------------------------------------------------------------
// Kernel 2: causal Taylor attention, bf16 MFMA, split-K across waves.
// phi(q).phi(k) = 1 + s + s^2/2, s = (q.k)/4.
// Grid: 512 blocks = (qt 0..31 heavy-first, bh 0..15). Block = 32 q-rows.
// Wave w handles key-chunks kc = w, w+4, ... (64 keys each): QK^T via
// mfma(K,Q) (f=16 -> zeroed hi frags), poly+mask+den on C-regs, pack bf16
// -> LDS P (wave-local, pitch 72 = conflict-free), PV with V-fragments
// straight from global Vtg (L2). Partials combined once via LDS scratch.
// ---------------------------------------------------------------------------
__global__ __launch_bounds__(256) void attn_mfma(
    const ushort* __restrict__ Qb, const ushort* __restrict__ Kb,
    const ushort* __restrict__ Vtg, ushort* __restrict__ Yb)
{
    __shared__ float smem[8864];   // 35456 B: P overlay (18432 B) / scratch (34816+512 B)
    short (*Pl)[32][72] = (short(*)[32][72])smem;   // [wave][q32][k64+8]
    float* scf = smem;             // epilogue: [4][32][68] f32 partial O
    float* scd = smem + 4*32*68;   // epilogue: [4][32] f32 partial den

    const int bid = blockIdx.x;
    const int qt = 31 - (bid & 31);       // heavy tiles dispatch first
    const int bh = bid >> 5;
    const int b = bh >> 3, h = bh & 7;
    const int tid = threadIdx.x, w = tid >> 6, l = tid & 63;
    const int lr = l & 15, g = l >> 4;
    const int nkc = (qt + 2) >> 1;        // ceil((qt+1)/2) 64-key chunks
    const bf16x8 zf = {0,0,0,0,0,0,0,0};

    // hoist Q B-fragments (f=16: lanes g>=2 hold zeros)
    bf16x8 qf[2];
    #pragma unroll
    for (int nb = 0; nb < 2; ++nb)
        qf[nb] = (l < 32)
            ? *(const bf16x8*)(Qb + ((size_t)bh*TT + qt*32 + nb*16 + lr)*FF + g*8)
            : zf;

    f32x4 o[4][2] = {};       // o[mv][nb]: O^T partial over this wave's kc set
    float den[2] = {0.f, 0.f};

    for (int kc = w; kc < nkc; kc += 4) {
        // S^T = K . Q^T for 64 keys; poly+mask+den; pack -> P
        #pragma unroll
        for (int mb = 0; mb < 4; ++mb) {
            bf16x8 kf = (l < 32)
                ? *(const bf16x8*)(Kb + ((size_t)bh*TT + kc*64 + mb*16 + lr)*FF + g*8)
                : zf;
            #pragma unroll
            for (int nb = 0; nb < 2; ++nb) {
                f32x4 z4 = {};
                f32x4 s = MFMA_BF16(kf, qf[nb], z4, 0, 0, 0);
                const int qg = qt*32 + nb*16 + lr;
                const int kg0 = kc*64 + mb*16 + g*4;
                float pv[4];
                #pragma unroll
                for (int r = 0; r < 4; ++r) {
                    float ss = s[r] * 0.25f;
                    float pp = fmaf(ss, fmaf(ss, 0.5f, 1.0f), 1.0f);
                    if (kg0 + r > qg) pp = 0.f;
                    den[nb] += pp;
                    pv[r] = pp;
                }
                uint2 pk = { (uint)f2b(pv[0]) | ((uint)f2b(pv[1]) << 16),
                             (uint)f2b(pv[2]) | ((uint)f2b(pv[3]) << 16) };
                *(uint2*)&Pl[w][nb*16 + lr][mb*16 + g*4] = pk;
            }
        }

        // O^T partial += V^T . P  (V fragments straight from global/L2)
        #pragma unroll
        for (int kb = 0; kb < 2; ++kb)
            #pragma unroll
            for (int mv = 0; mv < 4; ++mv) {
                bf16x8 vf = *(const bf16x8*)(Vtg +
                    ((size_t)bh*64 + mv*16 + lr)*TT + kc*64 + kb*32 + g*8);
                #pragma unroll
                for (int nb = 0; nb < 2; ++nb) {
                    bf16x8 pf = *(const bf16x8*)&Pl[w][nb*16 + lr][kb*32 + g*8];
                    o[mv][nb] = MFMA_BF16(vf, pf, o[mv][nb], 0, 0, 0);
                }
            }
    }

    // per-wave den reduce over lane groups (full den for this wave's kc set)
    float dred[2];
    #pragma unroll
    for (int nb = 0; nb < 2; ++nb) {
        float d = den[nb];
        d += __shfl_xor(d, 16);
        d += __shfl_xor(d, 32);
        dred[nb] = d;
    }

    __syncthreads();   // all waves done with Pl as bf16

    // dump partials to f32 scratch: scf[w][q][v], scd[w][q]
    #pragma unroll
    for (int mv = 0; mv < 4; ++mv)
        #pragma unroll
        for (int nb = 0; nb < 2; ++nb)
            *(f32x4*)&scf[((size_t)(w*32) + nb*16 + lr)*68 + mv*16 + g*4] = o[mv][nb];
    if (g == 0) {
        scd[w*32 + lr]      = dred[0];
        scd[w*32 + 16 + lr] = dred[1];
    }

    __syncthreads();

    // combine 4 wave-partials, normalize, store bf16 Y (coalesced 16B/thread)
    {
        const int q  = tid >> 3;            // 0..31
        const int v0 = (tid & 7) * 8;       // 0..56
        const float dtot = scd[q] + scd[32 + q] + scd[64 + q] + scd[96 + q];
        const float inv = 1.0f / (dtot + 1e-12f);
        float ov[8];
        #pragma unroll
        for (int j = 0; j < 8; ++j) ov[j] = 0.f;
        #pragma unroll
        for (int ww = 0; ww < 4; ++ww) {
            const float* p = &scf[((size_t)(ww*32) + q)*68 + v0];
            #pragma unroll
            for (int j = 0; j < 8; ++j) ov[j] += p[j];
        }
        uint4 pk;
        pk.x = (uint)f2b(ov[0]*inv) | ((uint)f2b(ov[1]*inv) << 16);
        pk.y = (uint)f2b(ov[2]*inv) | ((uint)f2b(ov[3]*inv) << 16);
        pk.z = (uint)f2b(ov[4]*inv) | ((uint)f2b(ov[5]*inv) << 16);
        pk.w = (uint)f2b(ov[6]*inv) | ((uint)f2b(ov[7]*inv) << 16);
        *(uint4*)(Yb + ((size_t)(b*TT + qt*32 + q))*DD + h*HDIM + v0) = pk;
    }
}

// ---------------------------------------------------------------------------
// Kernel 3: output projection, bf16 MFMA.  Out[2048 x 512] = Yb @ Wob^T, f32 out
// ---------------------------------------------------------------------------
__global__ __launch_bounds__(256) void out_mfma(
    const ushort* __restrict__ Yb, const ushort* __restrict__ Wob,
    float* __restrict__ Out)
{
    const int m0 = blockIdx.x * 64, n0 = blockIdx.y * 64;
    const int tid = threadIdx.x, w = tid >> 6, l = tid & 63;
    const int mw = w & 1, nw = w >> 1, lr = l & 15, g = l >> 4;

    f32x4 acc[2][2] = {};
    const ushort* Ar = Yb  + (size_t)(m0 + mw*32 + lr) * 512 + g*8;
    const ushort* Br = Wob + (size_t)(n0 + nw*32 + lr) * 512 + g*8;

    #pragma unroll 4
    for (int ks = 0; ks < 16; ++ks) {
        bf16x8 a0 = *(const bf16x8*)(Ar + ks*32);
        bf16x8 a1 = *(const bf16x8*)(Ar + (size_t)16*512 + ks*32);
        bf16x8 b0 = *(const bf16x8*)(Br + ks*32);
        bf16x8 b1 = *(const bf16x8*)(Br + (size_t)16*512 + ks*32);
        acc[0][0] = MFMA_BF16(a0, b0, acc[0][0], 0, 0, 0);
        acc[0][1] = MFMA_BF16(a0, b1, acc[0][1], 0, 0, 0);
        acc[1][0] = MFMA_BF16(a1, b0, acc[1][0], 0, 0, 0);
        acc[1][1] = MFMA_BF16(a1, b1, acc[1][1], 0, 0, 0);
    }

    #pragma unroll
    for (int mb = 0; mb < 2; ++mb)
        #pragma unroll
        for (int nb = 0; nb < 2; ++nb) {
            const int n = n0 + nw*32 + nb*16 + lr;
            const int m = m0 + mw*32 + mb*16 + g*4;
            #pragma unroll
            for (int r = 0; r < 4; ++r)
                Out[(size_t)(m + r)*512 + n] = acc[mb][nb][r];
        }
}

// ---------------------------------------------------------------------------
extern "C" void kernel_launch(void* const* d_in, const int* in_sizes, int n_in,
                              void* d_out, int out_size, void* d_ws, size_t ws_size,
                              hipStream_t stream) {
    const float* X  = (const float*)d_in[0];   // (2,1024,512)
    const float* Wq = (const float*)d_in[1];   // (128,512)
    const float* Wk = (const float*)d_in[2];   // (128,512)
    const float* Wv = (const float*)d_in[3];   // (512,512)
    const float* Wo = (const float*)d_in[4];   // (512,512)
    float* out = (float*)d_out;                // (2,1024,512)

    ushort* ws = (ushort*)d_ws;
    ushort* Xb  = ws;                    // 2048*512   = 1048576
    ushort* Wb  = Xb  + 1048576;         // 768*512    = 393216
    ushort* Wob = Wb  + 393216;          // 512*512    = 262144
    ushort* Qb  = Wob + 262144;          // 16*1024*16 = 262144
    ushort* Kb  = Qb  + 262144;          // 262144
    ushort* Vtg = Kb  + 262144;          // 16*64*1024 = 1048576
    ushort* Yb  = Vtg + 1048576;         // 2048*512   = 1048576

    cast_all<<<1664, 256, 0, stream>>>(X, Wq, Wk, Wv, Wo, Xb, Wb, Wob);

    dim3 g1(BT/64, 768/128);  // 32 x 6 = 192
    qkv_mfma<<<g1, 256, 0, stream>>>(Xb, Wb, Qb, Kb, Vtg);

    attn_mfma<<<512, 256, 0, stream>>>(Qb, Kb, Vtg, Yb);

    dim3 g3(BT/64, DD/64);    // 32 x 8 = 256
    out_mfma<<<g3, 256, 0, stream>>>(Yb, Wob, out);
}